// Round 4
// baseline (159.329 us; speedup 1.0000x reference)
//
#include <hip/hip_runtime.h>
#include <hip/hip_cooperative_groups.h>
#include <stdint.h>

namespace cg = cooperative_groups;

typedef __bf16 bf16x8 __attribute__((ext_vector_type(8)));
typedef float f32x4 __attribute__((ext_vector_type(4)));

#define EPS 1e-5f

// ---- workspace layout (bytes) ----
#define OFF_STATS 0                        // 16 f32
#define OFF_XHI   256                      // 131072 ushort = 256 KB
#define OFF_XLO   (OFF_XHI + 262144)
#define OFF_Q     (OFF_XLO + 262144)       // q,k,v f32 128x2048 each = 1 MB each
#define OFF_AHI   (OFF_Q + 3145728)        // attn hi 128x2048 ushort = 512 KB
#define OFF_ALO   (OFF_AHI + 524288)
#define OFF_PART  (OFF_ALO + 524288)       // 4 x 128x1024 f32 = 2 MB
#define OFF_PROJ  (OFF_PART + 2097152)     // 512 KB (fallback path only)

static __device__ __forceinline__ unsigned short f2b(float f) {
  return __builtin_bit_cast(unsigned short, (__bf16)f);
}
static __device__ __forceinline__ void split2(float f, unsigned short& hi, unsigned short& lo) {
  __bf16 h = (__bf16)f;
  hi = __builtin_bit_cast(unsigned short, h);
  lo = f2b(f - (float)h);
}

__device__ __forceinline__ float wave_red(float v) {
#pragma unroll
  for (int o = 32; o > 0; o >>= 1) v += __shfl_down(v, o);
  return v;
}

#define GLDS16(g, l)                                             \
  __builtin_amdgcn_global_load_lds(                              \
      (const __attribute__((address_space(1))) void*)(g),        \
      (__attribute__((address_space(3))) void*)(l), 16, 0, 0)

#define LOADW(WARR, SRC)                         \
  do {                                           \
    float4 a_ = *(const float4*)(SRC);           \
    float4 b_ = *(const float4*)((SRC) + 4);     \
    WARR[0] = a_.x; WARR[1] = a_.y; WARR[2] = a_.z; WARR[3] = a_.w; \
    WARR[4] = b_.x; WARR[5] = b_.y; WARR[6] = b_.z; WARR[7] = b_.w; \
  } while (0)

#define CVT_STORE(BUFIDX, WARR)                                         \
  do {                                                                  \
    uint4 ph_, pl_;                                                     \
    unsigned short h0_, l0_, h1_, l1_;                                  \
    split2(WARR[0], h0_, l0_); split2(WARR[1], h1_, l1_);               \
    ph_.x = (unsigned)h0_ | ((unsigned)h1_ << 16);                      \
    pl_.x = (unsigned)l0_ | ((unsigned)l1_ << 16);                      \
    split2(WARR[2], h0_, l0_); split2(WARR[3], h1_, l1_);               \
    ph_.y = (unsigned)h0_ | ((unsigned)h1_ << 16);                      \
    pl_.y = (unsigned)l0_ | ((unsigned)l1_ << 16);                      \
    split2(WARR[4], h0_, l0_); split2(WARR[5], h1_, l1_);               \
    ph_.z = (unsigned)h0_ | ((unsigned)h1_ << 16);                      \
    pl_.z = (unsigned)l0_ | ((unsigned)l1_ << 16);                      \
    split2(WARR[6], h0_, l0_); split2(WARR[7], h1_, l1_);               \
    ph_.w = (unsigned)h0_ | ((unsigned)h1_ << 16);                      \
    pl_.w = (unsigned)l0_ | ((unsigned)l1_ << 16);                      \
    *(uint4*)(&Bh[BUFIDX][wdst]) = ph_;                                 \
    *(uint4*)(&Bl[BUFIDX][wdst]) = pl_;                                 \
  } while (0)

// ===================== fused cooperative mega-kernel =====================
__global__ __launch_bounds__(256, 1) void fused_kernel(
    const float* __restrict__ x,
    const float* __restrict__ Wq, const float* __restrict__ Wk,
    const float* __restrict__ Wv, const float* __restrict__ Wo,
    const float* __restrict__ bo,
    const float* __restrict__ g_q, const float* __restrict__ b_q,
    const float* __restrict__ g_k, const float* __restrict__ b_k,
    const float* __restrict__ g_v, const float* __restrict__ b_v,
    const float* __restrict__ g_bn, const float* __restrict__ b_bn,
    float* __restrict__ out, char* __restrict__ ws) {
  __shared__ alignas(16) ushort Ah[2][128 * 64];
  __shared__ alignas(16) ushort Al[2][128 * 64];
  __shared__ alignas(16) ushort Bh[2][32 * 64];
  __shared__ alignas(16) ushort Bl[2][32 * 64];
  __shared__ float sred[16];
  __shared__ float sbc[4];

  float*  stats = (float*)(ws + OFF_STATS);
  ushort* xhi   = (ushort*)(ws + OFF_XHI);
  ushort* xlo   = (ushort*)(ws + OFF_XLO);
  float*  qkv   = (float*)(ws + OFF_Q);
  ushort* ahi   = (ushort*)(ws + OFF_AHI);
  ushort* alo   = (ushort*)(ws + OFF_ALO);
  float*  part  = (float*)(ws + OFF_PART);

  cg::grid_group gg = cg::this_grid();
  const int bid = blockIdx.x;
  const int tid = threadIdx.x;
  const int w = tid >> 6, lane = tid & 63;

  // ---------------- P0: split x into hi/lo bf16, zero stats ----------------
  if (bid < 128) {
    int i = bid * 1024 + tid * 4;
    float4 v = *(const float4*)(x + i);
    ushort4 h, l;
    split2(v.x, h.x, l.x); split2(v.y, h.y, l.y);
    split2(v.z, h.z, l.z); split2(v.w, h.w, l.w);
    *(ushort4*)(xhi + i) = h;
    *(ushort4*)(xlo + i) = l;
    if (bid == 0 && tid < 16) stats[tid] = 0.f;
  }
  gg.sync();

  // ---------------- P1: fused Q/K/V GEMM (all 192 blocks) ----------------
  {
    int mat = bid >> 6;
    int nt  = bid & 63;
    const float* W = (mat == 0) ? Wq : ((mat == 1) ? Wk : Wv);
    float* outp = qkv + mat * 262144;

    int l3 = lane >> 3, c7 = lane & 7;
    int swzc = (c7 ^ (l3 & 7)) << 3;
    int wr2 = tid >> 3, wq2 = tid & 7;
    const float* wsrc = W + (nt * 32 + wr2) * 1024 + wq2 * 8;
    int wdst = wr2 * 64 + ((wq2 ^ (wr2 & 7)) << 3);

    f32x4 acc[2][2];
#pragma unroll
    for (int m = 0; m < 2; ++m)
#pragma unroll
      for (int n = 0; n < 2; ++n) acc[m][n] = (f32x4){0.f, 0.f, 0.f, 0.f};

    float wreg0[8], wreg1[8];

#pragma unroll
    for (int j = 0; j < 4; ++j) {
      int row = (w * 4 + j) * 8 + l3;
      GLDS16(xhi + row * 1024 + 0 * 64 + swzc, &Ah[0][(w * 4 + j) * 512]);
      GLDS16(xlo + row * 1024 + 0 * 64 + swzc, &Al[0][(w * 4 + j) * 512]);
    }
    LOADW(wreg0, wsrc + 0 * 64);
#pragma unroll
    for (int j = 0; j < 4; ++j) {
      int row = (w * 4 + j) * 8 + l3;
      GLDS16(xhi + row * 1024 + 1 * 64 + swzc, &Ah[1][(w * 4 + j) * 512]);
      GLDS16(xlo + row * 1024 + 1 * 64 + swzc, &Al[1][(w * 4 + j) * 512]);
    }
    LOADW(wreg1, wsrc + 1 * 64);
    CVT_STORE(0, wreg0);
    __syncthreads();

#pragma unroll
    for (int t = 0; t < 16; ++t) {
      const int c = t & 1;
      bf16x8 fah[2][2], fal[2][2], fbh[2][2], fbl[2][2];
#pragma unroll
      for (int ks = 0; ks < 2; ++ks) {
        int kc = ks * 4 + (lane >> 4);
#pragma unroll
        for (int m = 0; m < 2; ++m) {
          int r = w * 32 + m * 16 + (lane & 15);
          int sw = r * 64 + ((kc ^ (r & 7)) << 3);
          fah[ks][m] = *(const bf16x8*)(&Ah[c][sw]);
          fal[ks][m] = *(const bf16x8*)(&Al[c][sw]);
        }
#pragma unroll
        for (int n = 0; n < 2; ++n) {
          int r = n * 16 + (lane & 15);
          int sw = r * 64 + ((kc ^ (r & 7)) << 3);
          fbh[ks][n] = *(const bf16x8*)(&Bh[c][sw]);
          fbl[ks][n] = *(const bf16x8*)(&Bl[c][sw]);
        }
      }
      if (t < 14) {
        asm volatile("s_waitcnt lgkmcnt(0)" ::: "memory");
#pragma unroll
        for (int j = 0; j < 4; ++j) {
          int row = (w * 4 + j) * 8 + l3;
          GLDS16(xhi + row * 1024 + (t + 2) * 64 + swzc, &Ah[c][(w * 4 + j) * 512]);
          GLDS16(xlo + row * 1024 + (t + 2) * 64 + swzc, &Al[c][(w * 4 + j) * 512]);
        }
        if (c == 0) { LOADW(wreg0, wsrc + (t + 2) * 64); }
        else        { LOADW(wreg1, wsrc + (t + 2) * 64); }
      }
#pragma unroll
      for (int ks = 0; ks < 2; ++ks)
#pragma unroll
        for (int m = 0; m < 2; ++m)
#pragma unroll
          for (int n = 0; n < 2; ++n) {
            acc[m][n] = __builtin_amdgcn_mfma_f32_16x16x32_bf16(fah[ks][m], fbh[ks][n], acc[m][n], 0, 0, 0);
            acc[m][n] = __builtin_amdgcn_mfma_f32_16x16x32_bf16(fah[ks][m], fbl[ks][n], acc[m][n], 0, 0, 0);
            acc[m][n] = __builtin_amdgcn_mfma_f32_16x16x32_bf16(fal[ks][m], fbh[ks][n], acc[m][n], 0, 0, 0);
          }
      if (t < 15) {
        if (c == 0) { CVT_STORE(1, wreg1); }
        else        { CVT_STORE(0, wreg0); }
        __syncthreads();
      }
    }

    float s0 = 0, q0 = 0, s1 = 0, q1 = 0;
#pragma unroll
    for (int m = 0; m < 2; ++m)
#pragma unroll
      for (int n = 0; n < 2; ++n)
#pragma unroll
        for (int r = 0; r < 4; ++r) {
          int row = w * 32 + m * 16 + (lane >> 4) * 4 + r;
          int col = nt * 32 + n * 16 + (lane & 15);
          float v = acc[m][n][r];
          outp[row * 2048 + col] = v;
          if (r & 1) { s1 += v; q1 += v * v; } else { s0 += v; q0 += v * v; }
        }
    s0 = wave_red(s0); q0 = wave_red(q0); s1 = wave_red(s1); q1 = wave_red(q1);
    __syncthreads();
    if (lane == 0) { sred[w * 4 + 0] = s0; sred[w * 4 + 1] = q0; sred[w * 4 + 2] = s1; sred[w * 4 + 3] = q1; }
    __syncthreads();
    if (tid == 0) {
      float a0 = 0, a1 = 0, a2 = 0, a3 = 0;
      for (int i = 0; i < 4; ++i) { a0 += sred[i * 4 + 0]; a1 += sred[i * 4 + 1]; a2 += sred[i * 4 + 2]; a3 += sred[i * 4 + 3]; }
      atomicAdd(&stats[mat * 4 + 0], a0);
      atomicAdd(&stats[mat * 4 + 1], a1);
      atomicAdd(&stats[mat * 4 + 2], a2);
      atomicAdd(&stats[mat * 4 + 3], a3);
    }
  }
  gg.sync();

  // ---------------- P2: linear attention + BN affine ----------------
  if (bid < 128) {
    int b = bid >> 1, h = bid & 1;
    const float cnt = 131072.f;
    float qs[2], qo[2], kc_[2], ko[2], vs[2], vo[2];
#pragma unroll
    for (int c = 0; c < 2; ++c) {
      float m, var, inv;
      m = stats[0 + 2 * c] / cnt; var = stats[1 + 2 * c] / cnt - m * m; inv = rsqrtf(var + EPS);
      qs[c] = g_q[c] * inv; qo[c] = b_q[c] - m * qs[c];
      m = stats[4 + 2 * c] / cnt; var = stats[5 + 2 * c] / cnt - m * m; inv = rsqrtf(var + EPS);
      kc_[c] = g_k[c] * inv; ko[c] = b_k[c] - m * kc_[c];
      m = stats[8 + 2 * c] / cnt; var = stats[9 + 2 * c] / cnt - m * m; inv = rsqrtf(var + EPS);
      vs[c] = g_v[c] * inv; vo[c] = b_v[c] - m * vs[c];
    }

    const float* Q = qkv;
    const float* K = qkv + 262144;
    const float* V = qkv + 524288;
    const float* q0p = Q + (b * 2 + 0) * 2048 + h * 1024;
    const float* q1p = Q + (b * 2 + 1) * 2048 + h * 1024;
    const float* k0p = K + (b * 2 + 0) * 2048 + h * 1024;
    const float* k1p = K + (b * 2 + 1) * 2048 + h * 1024;
    const float* v0p = V + (b * 2 + 0) * 2048 + h * 1024;
    const float* v1p = V + (b * 2 + 1) * 2048 + h * 1024;

    float p00 = 0, p01 = 0, p10 = 0, p11 = 0;
#pragma unroll
    for (int i = 0; i < 4; ++i) {
      int d = tid + i * 256;
      float a0 = q0p[d] * qs[0] + qo[0];
      float a1 = q1p[d] * qs[1] + qo[1];
      float c0 = k0p[d] * kc_[0] + ko[0];
      float c1 = k1p[d] * kc_[1] + ko[1];
      p00 += a0 * c0; p01 += a0 * c1; p10 += a1 * c0; p11 += a1 * c1;
    }
    p00 = wave_red(p00); p01 = wave_red(p01); p10 = wave_red(p10); p11 = wave_red(p11);
    __syncthreads();
    if (lane == 0) { sred[w * 4 + 0] = p00; sred[w * 4 + 1] = p01; sred[w * 4 + 2] = p10; sred[w * 4 + 3] = p11; }
    __syncthreads();
    if (tid < 4) sbc[tid] = sred[0 + tid] + sred[4 + tid] + sred[8 + tid] + sred[12 + tid];
    __syncthreads();
    float s00 = sbc[0], s01 = sbc[1], s10 = sbc[2], s11 = sbc[3];
    float di0 = 1.f / (s00 + s01), di1 = 1.f / (s10 + s11);
    int o0 = (b * 2 + 0) * 2048 + h * 1024;
    int o1 = (b * 2 + 1) * 2048 + h * 1024;
#pragma unroll
    for (int i = 0; i < 4; ++i) {
      int d = tid + i * 256;
      float v0 = v0p[d] * vs[0] + vo[0];
      float v1 = v1p[d] * vs[1] + vo[1];
      float r0 = (s00 * v0 + s01 * v1) * di0;
      float r1 = (s10 * v0 + s11 * v1) * di1;
      unsigned short h_, l_;
      split2(r0, h_, l_); ahi[o0 + d] = h_; alo[o0 + d] = l_;
      split2(r1, h_, l_); ahi[o1 + d] = h_; alo[o1 + d] = l_;
    }
  }
  gg.sync();

  // ---------------- P3: out GEMM -> K-split partials ----------------
  if (bid < 128) {
    int nt  = bid & 31;
    int ksp = bid >> 5;
    float* outp = part + ksp * 131072;
    int kbase = ksp * 512;

    int l3 = lane >> 3, c7 = lane & 7;
    int swzc = (c7 ^ (l3 & 7)) << 3;
    int wr2 = tid >> 3, wq2 = tid & 7;
    const float* wsrc = Wo + (nt * 32 + wr2) * 2048 + kbase + wq2 * 8;
    int wdst = wr2 * 64 + ((wq2 ^ (wr2 & 7)) << 3);

    f32x4 acc[2][2];
#pragma unroll
    for (int m = 0; m < 2; ++m)
#pragma unroll
      for (int n = 0; n < 2; ++n) acc[m][n] = (f32x4){0.f, 0.f, 0.f, 0.f};

    float wreg0[8], wreg1[8];

#pragma unroll
    for (int j = 0; j < 4; ++j) {
      int row = (w * 4 + j) * 8 + l3;
      GLDS16(ahi + row * 2048 + kbase + 0 * 64 + swzc, &Ah[0][(w * 4 + j) * 512]);
      GLDS16(alo + row * 2048 + kbase + 0 * 64 + swzc, &Al[0][(w * 4 + j) * 512]);
    }
    LOADW(wreg0, wsrc + 0 * 64);
#pragma unroll
    for (int j = 0; j < 4; ++j) {
      int row = (w * 4 + j) * 8 + l3;
      GLDS16(ahi + row * 2048 + kbase + 1 * 64 + swzc, &Ah[1][(w * 4 + j) * 512]);
      GLDS16(alo + row * 2048 + kbase + 1 * 64 + swzc, &Al[1][(w * 4 + j) * 512]);
    }
    LOADW(wreg1, wsrc + 1 * 64);
    CVT_STORE(0, wreg0);
    __syncthreads();

#pragma unroll
    for (int t = 0; t < 8; ++t) {
      const int c = t & 1;
      bf16x8 fah[2][2], fal[2][2], fbh[2][2], fbl[2][2];
#pragma unroll
      for (int ks = 0; ks < 2; ++ks) {
        int kc = ks * 4 + (lane >> 4);
#pragma unroll
        for (int m = 0; m < 2; ++m) {
          int r = w * 32 + m * 16 + (lane & 15);
          int sw = r * 64 + ((kc ^ (r & 7)) << 3);
          fah[ks][m] = *(const bf16x8*)(&Ah[c][sw]);
          fal[ks][m] = *(const bf16x8*)(&Al[c][sw]);
        }
#pragma unroll
        for (int n = 0; n < 2; ++n) {
          int r = n * 16 + (lane & 15);
          int sw = r * 64 + ((kc ^ (r & 7)) << 3);
          fbh[ks][n] = *(const bf16x8*)(&Bh[c][sw]);
          fbl[ks][n] = *(const bf16x8*)(&Bl[c][sw]);
        }
      }
      if (t < 6) {
        asm volatile("s_waitcnt lgkmcnt(0)" ::: "memory");
#pragma unroll
        for (int j = 0; j < 4; ++j) {
          int row = (w * 4 + j) * 8 + l3;
          GLDS16(ahi + row * 2048 + kbase + (t + 2) * 64 + swzc, &Ah[c][(w * 4 + j) * 512]);
          GLDS16(alo + row * 2048 + kbase + (t + 2) * 64 + swzc, &Al[c][(w * 4 + j) * 512]);
        }
        if (c == 0) { LOADW(wreg0, wsrc + (t + 2) * 64); }
        else        { LOADW(wreg1, wsrc + (t + 2) * 64); }
      }
#pragma unroll
      for (int ks = 0; ks < 2; ++ks)
#pragma unroll
        for (int m = 0; m < 2; ++m)
#pragma unroll
          for (int n = 0; n < 2; ++n) {
            acc[m][n] = __builtin_amdgcn_mfma_f32_16x16x32_bf16(fah[ks][m], fbh[ks][n], acc[m][n], 0, 0, 0);
            acc[m][n] = __builtin_amdgcn_mfma_f32_16x16x32_bf16(fah[ks][m], fbl[ks][n], acc[m][n], 0, 0, 0);
            acc[m][n] = __builtin_amdgcn_mfma_f32_16x16x32_bf16(fal[ks][m], fbh[ks][n], acc[m][n], 0, 0, 0);
          }
      if (t < 7) {
        if (c == 0) { CVT_STORE(1, wreg1); }
        else        { CVT_STORE(0, wreg0); }
        __syncthreads();
      }
    }

#pragma unroll
    for (int m = 0; m < 2; ++m)
#pragma unroll
      for (int n = 0; n < 2; ++n)
#pragma unroll
        for (int r = 0; r < 4; ++r) {
          int row = w * 32 + m * 16 + (lane >> 4) * 4 + r;
          int col = nt * 32 + n * 16 + (lane & 15);
          outp[row * 1024 + col] = acc[m][n][r];
        }
  }
  gg.sync();

  // ---------------- P4: reduce partials + bias; keep row in regs; stats ----------------
  float pr0 = 0, pr1 = 0, pr2 = 0, pr3 = 0;
  if (bid < 128) {
    int r = bid;
    float s = 0, q = 0;
    {
      int cl = tid;
      float v = part[r * 1024 + cl] + part[131072 + r * 1024 + cl] +
                part[262144 + r * 1024 + cl] + part[393216 + r * 1024 + cl] + bo[cl];
      pr0 = v; s += v; q += v * v;
    }
    {
      int cl = tid + 256;
      float v = part[r * 1024 + cl] + part[131072 + r * 1024 + cl] +
                part[262144 + r * 1024 + cl] + part[393216 + r * 1024 + cl] + bo[cl];
      pr1 = v; s += v; q += v * v;
    }
    {
      int cl = tid + 512;
      float v = part[r * 1024 + cl] + part[131072 + r * 1024 + cl] +
                part[262144 + r * 1024 + cl] + part[393216 + r * 1024 + cl] + bo[cl];
      pr2 = v; s += v; q += v * v;
    }
    {
      int cl = tid + 768;
      float v = part[r * 1024 + cl] + part[131072 + r * 1024 + cl] +
                part[262144 + r * 1024 + cl] + part[393216 + r * 1024 + cl] + bo[cl];
      pr3 = v; s += v; q += v * v;
    }
    s = wave_red(s); q = wave_red(q);
    __syncthreads();
    if (lane == 0) { sred[w * 2] = s; sred[w * 2 + 1] = q; }
    __syncthreads();
    if (tid == 0) {
      float a = 0, b2 = 0;
      for (int i = 0; i < 4; ++i) { a += sred[i * 2]; b2 += sred[i * 2 + 1]; }
      atomicAdd(&stats[12 + 2 * (r & 1)], a);
      atomicAdd(&stats[13 + 2 * (r & 1)], b2);
    }
  }
  gg.sync();

  // ---------------- P5: final BN normalize from registers ----------------
  if (bid < 128) {
    int r = bid, ch = r & 1;
    float m = stats[12 + 2 * ch] / 65536.f;
    float var = stats[13 + 2 * ch] / 65536.f - m * m;
    float sc = g_bn[ch] * rsqrtf(var + EPS);
    float sh = b_bn[ch] - m * sc;
    out[r * 1024 + tid]       = pr0 * sc + sh;
    out[r * 1024 + tid + 256] = pr1 * sc + sh;
    out[r * 1024 + tid + 512] = pr2 * sc + sh;
    out[r * 1024 + tid + 768] = pr3 * sc + sh;
  }
}

// ===================== fallback path (round-3 kernels, verified) =====================

__global__ __launch_bounds__(256) void prep_kernel(const float* __restrict__ x,
                                                   ushort* __restrict__ xhi,
                                                   ushort* __restrict__ xlo,
                                                   float* __restrict__ stats) {
  int i = blockIdx.x * 1024 + threadIdx.x * 4;
  float4 v = *(const float4*)(x + i);
  ushort4 h, l;
  split2(v.x, h.x, l.x); split2(v.y, h.y, l.y);
  split2(v.z, h.z, l.z); split2(v.w, h.w, l.w);
  *(ushort4*)(xhi + i) = h;
  *(ushort4*)(xlo + i) = l;
  if (blockIdx.x == 0 && threadIdx.x < 16) stats[threadIdx.x] = 0.f;
}

__global__ __launch_bounds__(256, 2) void qkv_gemm(const ushort* __restrict__ xhi,
                                                   const ushort* __restrict__ xlo,
                                                   const float* __restrict__ Wq,
                                                   const float* __restrict__ Wk,
                                                   const float* __restrict__ Wv,
                                                   float* __restrict__ qkv,
                                                   float* __restrict__ stats) {
  __shared__ alignas(16) ushort Ah[2][128 * 64];
  __shared__ alignas(16) ushort Al[2][128 * 64];
  __shared__ alignas(16) ushort Bh[2][32 * 64];
  __shared__ alignas(16) ushort Bl[2][32 * 64];
  __shared__ float red[16];

  int mat = blockIdx.x >> 6;
  int nt  = blockIdx.x & 63;
  const float* W = (mat == 0) ? Wq : ((mat == 1) ? Wk : Wv);
  float* outp = qkv + mat * 262144;

  int tid = threadIdx.x, w = tid >> 6, lane = tid & 63;
  int l3 = lane >> 3, c7 = lane & 7;
  int swzc = (c7 ^ (l3 & 7)) << 3;
  int wr2 = tid >> 3, wq2 = tid & 7;
  const float* wsrc = W + (nt * 32 + wr2) * 1024 + wq2 * 8;
  int wdst = wr2 * 64 + ((wq2 ^ (wr2 & 7)) << 3);

  f32x4 acc[2][2];
#pragma unroll
  for (int m = 0; m < 2; ++m)
#pragma unroll
    for (int n = 0; n < 2; ++n) acc[m][n] = (f32x4){0.f, 0.f, 0.f, 0.f};

  float wreg0[8], wreg1[8];

#pragma unroll
  for (int j = 0; j < 4; ++j) {
    int row = (w * 4 + j) * 8 + l3;
    GLDS16(xhi + row * 1024 + 0 * 64 + swzc, &Ah[0][(w * 4 + j) * 512]);
    GLDS16(xlo + row * 1024 + 0 * 64 + swzc, &Al[0][(w * 4 + j) * 512]);
  }
  LOADW(wreg0, wsrc + 0 * 64);
#pragma unroll
  for (int j = 0; j < 4; ++j) {
    int row = (w * 4 + j) * 8 + l3;
    GLDS16(xhi + row * 1024 + 1 * 64 + swzc, &Ah[1][(w * 4 + j) * 512]);
    GLDS16(xlo + row * 1024 + 1 * 64 + swzc, &Al[1][(w * 4 + j) * 512]);
  }
  LOADW(wreg1, wsrc + 1 * 64);
  CVT_STORE(0, wreg0);
  __syncthreads();

#pragma unroll
  for (int t = 0; t < 16; ++t) {
    const int c = t & 1;
    bf16x8 fah[2][2], fal[2][2], fbh[2][2], fbl[2][2];
#pragma unroll
    for (int ks = 0; ks < 2; ++ks) {
      int kc = ks * 4 + (lane >> 4);
#pragma unroll
      for (int m = 0; m < 2; ++m) {
        int r = w * 32 + m * 16 + (lane & 15);
        int sw = r * 64 + ((kc ^ (r & 7)) << 3);
        fah[ks][m] = *(const bf16x8*)(&Ah[c][sw]);
        fal[ks][m] = *(const bf16x8*)(&Al[c][sw]);
      }
#pragma unroll
      for (int n = 0; n < 2; ++n) {
        int r = n * 16 + (lane & 15);
        int sw = r * 64 + ((kc ^ (r & 7)) << 3);
        fbh[ks][n] = *(const bf16x8*)(&Bh[c][sw]);
        fbl[ks][n] = *(const bf16x8*)(&Bl[c][sw]);
      }
    }
    if (t < 14) {
      asm volatile("s_waitcnt lgkmcnt(0)" ::: "memory");
#pragma unroll
      for (int j = 0; j < 4; ++j) {
        int row = (w * 4 + j) * 8 + l3;
        GLDS16(xhi + row * 1024 + (t + 2) * 64 + swzc, &Ah[c][(w * 4 + j) * 512]);
        GLDS16(xlo + row * 1024 + (t + 2) * 64 + swzc, &Al[c][(w * 4 + j) * 512]);
      }
      if (c == 0) { LOADW(wreg0, wsrc + (t + 2) * 64); }
      else        { LOADW(wreg1, wsrc + (t + 2) * 64); }
    }
#pragma unroll
    for (int ks = 0; ks < 2; ++ks)
#pragma unroll
      for (int m = 0; m < 2; ++m)
#pragma unroll
        for (int n = 0; n < 2; ++n) {
          acc[m][n] = __builtin_amdgcn_mfma_f32_16x16x32_bf16(fah[ks][m], fbh[ks][n], acc[m][n], 0, 0, 0);
          acc[m][n] = __builtin_amdgcn_mfma_f32_16x16x32_bf16(fah[ks][m], fbl[ks][n], acc[m][n], 0, 0, 0);
          acc[m][n] = __builtin_amdgcn_mfma_f32_16x16x32_bf16(fal[ks][m], fbh[ks][n], acc[m][n], 0, 0, 0);
        }
    if (t < 15) {
      if (c == 0) { CVT_STORE(1, wreg1); }
      else        { CVT_STORE(0, wreg0); }
      __syncthreads();
    }
  }

  float s0 = 0, q0 = 0, s1 = 0, q1 = 0;
#pragma unroll
  for (int m = 0; m < 2; ++m)
#pragma unroll
    for (int n = 0; n < 2; ++n)
#pragma unroll
      for (int r = 0; r < 4; ++r) {
        int row = w * 32 + m * 16 + (lane >> 4) * 4 + r;
        int col = nt * 32 + n * 16 + (lane & 15);
        float v = acc[m][n][r];
        outp[row * 2048 + col] = v;
        if (r & 1) { s1 += v; q1 += v * v; } else { s0 += v; q0 += v * v; }
      }
  s0 = wave_red(s0); q0 = wave_red(q0); s1 = wave_red(s1); q1 = wave_red(q1);
  if (lane == 0) { red[w * 4 + 0] = s0; red[w * 4 + 1] = q0; red[w * 4 + 2] = s1; red[w * 4 + 3] = q1; }
  __syncthreads();
  if (tid == 0) {
    float a0 = 0, a1 = 0, a2 = 0, a3 = 0;
    for (int i = 0; i < 4; ++i) { a0 += red[i * 4 + 0]; a1 += red[i * 4 + 1]; a2 += red[i * 4 + 2]; a3 += red[i * 4 + 3]; }
    atomicAdd(&stats[mat * 4 + 0], a0);
    atomicAdd(&stats[mat * 4 + 1], a1);
    atomicAdd(&stats[mat * 4 + 2], a2);
    atomicAdd(&stats[mat * 4 + 3], a3);
  }
}

__global__ __launch_bounds__(256) void attn_kernel(const float* __restrict__ qkv,
                                                   const float* __restrict__ stats,
                                                   ushort* __restrict__ ahi,
                                                   ushort* __restrict__ alo,
                                                   const float* __restrict__ g_q, const float* __restrict__ b_q,
                                                   const float* __restrict__ g_k, const float* __restrict__ b_k,
                                                   const float* __restrict__ g_v, const float* __restrict__ b_v) {
  __shared__ float red[16];
  __shared__ float bc[4];
  int bh = blockIdx.x, b = bh >> 1, h = bh & 1;
  int tid = threadIdx.x, w = tid >> 6, lane = tid & 63;

  const float cnt = 131072.f;
  float qs[2], qo[2], kc_[2], ko[2], vs[2], vo[2];
#pragma unroll
  for (int c = 0; c < 2; ++c) {
    float m, var, inv;
    m = stats[0 + 2 * c] / cnt; var = stats[1 + 2 * c] / cnt - m * m; inv = rsqrtf(var + EPS);
    qs[c] = g_q[c] * inv; qo[c] = b_q[c] - m * qs[c];
    m = stats[4 + 2 * c] / cnt; var = stats[5 + 2 * c] / cnt - m * m; inv = rsqrtf(var + EPS);
    kc_[c] = g_k[c] * inv; ko[c] = b_k[c] - m * kc_[c];
    m = stats[8 + 2 * c] / cnt; var = stats[9 + 2 * c] / cnt - m * m; inv = rsqrtf(var + EPS);
    vs[c] = g_v[c] * inv; vo[c] = b_v[c] - m * vs[c];
  }

  const float* Q = qkv;
  const float* K = qkv + 262144;
  const float* V = qkv + 524288;
  const float* q0p = Q + (b * 2 + 0) * 2048 + h * 1024;
  const float* q1p = Q + (b * 2 + 1) * 2048 + h * 1024;
  const float* k0p = K + (b * 2 + 0) * 2048 + h * 1024;
  const float* k1p = K + (b * 2 + 1) * 2048 + h * 1024;
  const float* v0p = V + (b * 2 + 0) * 2048 + h * 1024;
  const float* v1p = V + (b * 2 + 1) * 2048 + h * 1024;

  float p00 = 0, p01 = 0, p10 = 0, p11 = 0;
#pragma unroll
  for (int i = 0; i < 4; ++i) {
    int d = tid + i * 256;
    float a0 = q0p[d] * qs[0] + qo[0];
    float a1 = q1p[d] * qs[1] + qo[1];
    float c0 = k0p[d] * kc_[0] + ko[0];
    float c1 = k1p[d] * kc_[1] + ko[1];
    p00 += a0 * c0; p01 += a0 * c1; p10 += a1 * c0; p11 += a1 * c1;
  }
  p00 = wave_red(p00); p01 = wave_red(p01); p10 = wave_red(p10); p11 = wave_red(p11);
  if (lane == 0) { red[w * 4 + 0] = p00; red[w * 4 + 1] = p01; red[w * 4 + 2] = p10; red[w * 4 + 3] = p11; }
  __syncthreads();
  if (tid < 4) bc[tid] = red[0 + tid] + red[4 + tid] + red[8 + tid] + red[12 + tid];
  __syncthreads();
  float s00 = bc[0], s01 = bc[1], s10 = bc[2], s11 = bc[3];
  float di0 = 1.f / (s00 + s01), di1 = 1.f / (s10 + s11);
  int o0 = (b * 2 + 0) * 2048 + h * 1024;
  int o1 = (b * 2 + 1) * 2048 + h * 1024;
#pragma unroll
  for (int i = 0; i < 4; ++i) {
    int d = tid + i * 256;
    float v0 = v0p[d] * vs[0] + vo[0];
    float v1 = v1p[d] * vs[1] + vo[1];
    float r0 = (s00 * v0 + s01 * v1) * di0;
    float r1 = (s10 * v0 + s11 * v1) * di1;
    unsigned short h_, l_;
    split2(r0, h_, l_); ahi[o0 + d] = h_; alo[o0 + d] = l_;
    split2(r1, h_, l_); ahi[o1 + d] = h_; alo[o1 + d] = l_;
  }
}

__global__ __launch_bounds__(256, 2) void out_gemm(const ushort* __restrict__ ahi_g,
                                                   const ushort* __restrict__ alo_g,
                                                   const float* __restrict__ Wo,
                                                   float* __restrict__ part) {
  __shared__ alignas(16) ushort Ah[2][128 * 64];
  __shared__ alignas(16) ushort Al[2][128 * 64];
  __shared__ alignas(16) ushort Bh[2][32 * 64];
  __shared__ alignas(16) ushort Bl[2][32 * 64];

  int nt  = blockIdx.x & 31;
  int ksp = blockIdx.x >> 5;
  float* outp = part + ksp * 131072;
  int kbase = ksp * 512;

  int tid = threadIdx.x, w = tid >> 6, lane = tid & 63;
  int l3 = lane >> 3, c7 = lane & 7;
  int swzc = (c7 ^ (l3 & 7)) << 3;
  int wr2 = tid >> 3, wq2 = tid & 7;
  const float* wsrc = Wo + (nt * 32 + wr2) * 2048 + kbase + wq2 * 8;
  int wdst = wr2 * 64 + ((wq2 ^ (wr2 & 7)) << 3);

  f32x4 acc[2][2];
#pragma unroll
  for (int m = 0; m < 2; ++m)
#pragma unroll
    for (int n = 0; n < 2; ++n) acc[m][n] = (f32x4){0.f, 0.f, 0.f, 0.f};

  float wreg0[8], wreg1[8];

#pragma unroll
  for (int j = 0; j < 4; ++j) {
    int row = (w * 4 + j) * 8 + l3;
    GLDS16(ahi_g + row * 2048 + kbase + 0 * 64 + swzc, &Ah[0][(w * 4 + j) * 512]);
    GLDS16(alo_g + row * 2048 + kbase + 0 * 64 + swzc, &Al[0][(w * 4 + j) * 512]);
  }
  LOADW(wreg0, wsrc + 0 * 64);
#pragma unroll
  for (int j = 0; j < 4; ++j) {
    int row = (w * 4 + j) * 8 + l3;
    GLDS16(ahi_g + row * 2048 + kbase + 1 * 64 + swzc, &Ah[1][(w * 4 + j) * 512]);
    GLDS16(alo_g + row * 2048 + kbase + 1 * 64 + swzc, &Al[1][(w * 4 + j) * 512]);
  }
  LOADW(wreg1, wsrc + 1 * 64);
  CVT_STORE(0, wreg0);
  __syncthreads();

#pragma unroll
  for (int t = 0; t < 8; ++t) {
    const int c = t & 1;
    bf16x8 fah[2][2], fal[2][2], fbh[2][2], fbl[2][2];
#pragma unroll
    for (int ks = 0; ks < 2; ++ks) {
      int kc = ks * 4 + (lane >> 4);
#pragma unroll
      for (int m = 0; m < 2; ++m) {
        int r = w * 32 + m * 16 + (lane & 15);
        int sw = r * 64 + ((kc ^ (r & 7)) << 3);
        fah[ks][m] = *(const bf16x8*)(&Ah[c][sw]);
        fal[ks][m] = *(const bf16x8*)(&Al[c][sw]);
      }
#pragma unroll
      for (int n = 0; n < 2; ++n) {
        int r = n * 16 + (lane & 15);
        int sw = r * 64 + ((kc ^ (r & 7)) << 3);
        fbh[ks][n] = *(const bf16x8*)(&Bh[c][sw]);
        fbl[ks][n] = *(const bf16x8*)(&Bl[c][sw]);
      }
    }
    if (t < 6) {
      asm volatile("s_waitcnt lgkmcnt(0)" ::: "memory");
#pragma unroll
      for (int j = 0; j < 4; ++j) {
        int row = (w * 4 + j) * 8 + l3;
        GLDS16(ahi_g + row * 2048 + kbase + (t + 2) * 64 + swzc, &Ah[c][(w * 4 + j) * 512]);
        GLDS16(alo_g + row * 2048 + kbase + (t + 2) * 64 + swzc, &Al[c][(w * 4 + j) * 512]);
      }
      if (c == 0) { LOADW(wreg0, wsrc + (t + 2) * 64); }
      else        { LOADW(wreg1, wsrc + (t + 2) * 64); }
    }
#pragma unroll
    for (int ks = 0; ks < 2; ++ks)
#pragma unroll
      for (int m = 0; m < 2; ++m)
#pragma unroll
        for (int n = 0; n < 2; ++n) {
          acc[m][n] = __builtin_amdgcn_mfma_f32_16x16x32_bf16(fah[ks][m], fbh[ks][n], acc[m][n], 0, 0, 0);
          acc[m][n] = __builtin_amdgcn_mfma_f32_16x16x32_bf16(fah[ks][m], fbl[ks][n], acc[m][n], 0, 0, 0);
          acc[m][n] = __builtin_amdgcn_mfma_f32_16x16x32_bf16(fal[ks][m], fbh[ks][n], acc[m][n], 0, 0, 0);
        }
    if (t < 7) {
      if (c == 0) { CVT_STORE(1, wreg1); }
      else        { CVT_STORE(0, wreg0); }
      __syncthreads();
    }
  }

#pragma unroll
  for (int m = 0; m < 2; ++m)
#pragma unroll
    for (int n = 0; n < 2; ++n)
#pragma unroll
      for (int r = 0; r < 4; ++r) {
        int row = w * 32 + m * 16 + (lane >> 4) * 4 + r;
        int col = nt * 32 + n * 16 + (lane & 15);
        outp[row * 1024 + col] = acc[m][n][r];
      }
}

__global__ __launch_bounds__(256) void reduce_kernel(const float* __restrict__ part,
                                                     const float* __restrict__ bo,
                                                     float* __restrict__ proj,
                                                     float* __restrict__ stats) {
  __shared__ float red[8];
  int r = blockIdx.x, tid = threadIdx.x, w = tid >> 6, lane = tid & 63;
  float s = 0, q = 0;
#pragma unroll
  for (int i = 0; i < 4; ++i) {
    int c = tid + i * 256;
    float v = part[r * 1024 + c] + part[131072 + r * 1024 + c] +
              part[262144 + r * 1024 + c] + part[393216 + r * 1024 + c] + bo[c];
    proj[r * 1024 + c] = v;
    s += v; q += v * v;
  }
  s = wave_red(s); q = wave_red(q);
  if (lane == 0) { red[w * 2] = s; red[w * 2 + 1] = q; }
  __syncthreads();
  if (tid == 0) {
    float a = 0, bq = 0;
    for (int i = 0; i < 4; ++i) { a += red[i * 2]; bq += red[i * 2 + 1]; }
    atomicAdd(&stats[12 + 2 * (r & 1)], a);
    atomicAdd(&stats[13 + 2 * (r & 1)], bq);
  }
}

__global__ __launch_bounds__(256) void final_kernel(const float* __restrict__ proj,
                                                    const float* __restrict__ stats,
                                                    const float* __restrict__ g_bn,
                                                    const float* __restrict__ b_bn,
                                                    float* __restrict__ out) {
  int i = blockIdx.x * 1024 + threadIdx.x * 4;
  int ch = (i >> 10) & 1;
  float m = stats[12 + 2 * ch] / 65536.f;
  float var = stats[13 + 2 * ch] / 65536.f - m * m;
  float sc = g_bn[ch] * rsqrtf(var + EPS);
  float sh = b_bn[ch] - m * sc;
  float4 v = *(const float4*)(proj + i);
  float4 o = {v.x * sc + sh, v.y * sc + sh, v.z * sc + sh, v.w * sc + sh};
  *(float4*)(out + i) = o;
}

extern "C" void kernel_launch(void* const* d_in, const int* in_sizes, int n_in,
                              void* d_out, int out_size, void* d_ws, size_t ws_size,
                              hipStream_t stream) {
  (void)in_sizes; (void)n_in; (void)out_size; (void)ws_size;
  const float* x    = (const float*)d_in[0];
  const float* Wq   = (const float*)d_in[1];
  const float* Wk   = (const float*)d_in[2];
  const float* Wv   = (const float*)d_in[3];
  const float* Wo   = (const float*)d_in[4];
  const float* bo   = (const float*)d_in[5];
  const float* g_q  = (const float*)d_in[6];
  const float* b_q  = (const float*)d_in[7];
  const float* g_k  = (const float*)d_in[8];
  const float* b_k  = (const float*)d_in[9];
  const float* g_v  = (const float*)d_in[10];
  const float* b_v  = (const float*)d_in[11];
  const float* g_bn = (const float*)d_in[12];
  const float* b_bn = (const float*)d_in[13];
  char* wsc = (char*)d_ws;
  float* out = (float*)d_out;

  void* args[16] = {
    (void*)&x, (void*)&Wq, (void*)&Wk, (void*)&Wv, (void*)&Wo, (void*)&bo,
    (void*)&g_q, (void*)&b_q, (void*)&g_k, (void*)&b_k, (void*)&g_v, (void*)&b_v,
    (void*)&g_bn, (void*)&b_bn, (void*)&out, (void*)&wsc
  };
  hipError_t e = hipLaunchCooperativeKernel((void*)fused_kernel, dim3(192), dim3(256),
                                            args, 0, stream);
  if (e != hipSuccess) {
    // fallback: verified 6-kernel path
    float*  stats = (float*)(wsc + OFF_STATS);
    ushort* xhi   = (ushort*)(wsc + OFF_XHI);
    ushort* xlo   = (ushort*)(wsc + OFF_XLO);
    float*  qkv   = (float*)(wsc + OFF_Q);
    ushort* ahi   = (ushort*)(wsc + OFF_AHI);
    ushort* alo   = (ushort*)(wsc + OFF_ALO);
    float*  part  = (float*)(wsc + OFF_PART);
    float*  proj  = (float*)(wsc + OFF_PROJ);

    hipLaunchKernelGGL(prep_kernel,   dim3(128), dim3(256), 0, stream, x, xhi, xlo, stats);
    hipLaunchKernelGGL(qkv_gemm,      dim3(192), dim3(256), 0, stream, xhi, xlo, Wq, Wk, Wv, qkv, stats);
    hipLaunchKernelGGL(attn_kernel,   dim3(128), dim3(256), 0, stream, qkv, stats, ahi, alo,
                       g_q, b_q, g_k, b_k, g_v, b_v);
    hipLaunchKernelGGL(out_gemm,      dim3(128), dim3(256), 0, stream, ahi, alo, Wo, part);
    hipLaunchKernelGGL(reduce_kernel, dim3(128), dim3(256), 0, stream, part, bo, proj, stats);
    hipLaunchKernelGGL(final_kernel,  dim3(128), dim3(256), 0, stream, proj, stats, g_bn, b_bn, out);
  }
}

// Round 5
// 56.489 us; speedup vs baseline: 2.8205x; 2.8205x over previous
//
#include <hip/hip_runtime.h>
#include <stdint.h>

typedef __bf16 bf16x8 __attribute__((ext_vector_type(8)));
typedef float f32x4 __attribute__((ext_vector_type(4)));

#define EPS 1e-5f

// ---- workspace layout (bytes) ----
#define OFF_STATS 0                        // 16 f32 (q/k/v BN stats via atomics)
#define OFF_XHI   256                      // 131072 ushort = 256 KB
#define OFF_XLO   (OFF_XHI + 262144)
#define OFF_Q     (OFF_XLO + 262144)       // q,k,v f32 128x2048 each = 1 MB each
#define OFF_AHI   (OFF_Q + 3145728)        // attn hi 128x2048 ushort = 512 KB
#define OFF_ALO   (OFF_AHI + 524288)
#define OFF_SO    (OFF_ALO + 524288)       // 128 x 4 f32 out-BN partials = 2 KB
#define OFF_PROJ  (OFF_SO + 4096)          // 128x1024 f32 = 512 KB

static __device__ __forceinline__ unsigned short f2b(float f) {
  return __builtin_bit_cast(unsigned short, (__bf16)f);
}
static __device__ __forceinline__ void split2(float f, unsigned short& hi, unsigned short& lo) {
  __bf16 h = (__bf16)f;
  hi = __builtin_bit_cast(unsigned short, h);
  lo = f2b(f - (float)h);
}

__device__ __forceinline__ float wave_red(float v) {
#pragma unroll
  for (int o = 32; o > 0; o >>= 1) v += __shfl_down(v, o);
  return v;
}

#define GLDS16(g, l)                                             \
  __builtin_amdgcn_global_load_lds(                              \
      (const __attribute__((address_space(1))) void*)(g),        \
      (__attribute__((address_space(3))) void*)(l), 16, 0, 0)

// K0: split x into hi/lo bf16, zero stats
__global__ __launch_bounds__(256) void prep_kernel(const float* __restrict__ x,
                                                   ushort* __restrict__ xhi,
                                                   ushort* __restrict__ xlo,
                                                   float* __restrict__ stats) {
  int i = blockIdx.x * 1024 + threadIdx.x * 4;
  float4 v = *(const float4*)(x + i);
  ushort4 h, l;
  split2(v.x, h.x, l.x); split2(v.y, h.y, l.y);
  split2(v.z, h.z, l.z); split2(v.w, h.w, l.w);
  *(ushort4*)(xhi + i) = h;
  *(ushort4*)(xlo + i) = l;
  if (blockIdx.x == 0 && threadIdx.x < 16) stats[threadIdx.x] = 0.f;
}

// ---- staging macros ----
#define LOADW(WARR, SRC)                         \
  do {                                           \
    float4 a_ = *(const float4*)(SRC);           \
    float4 b_ = *(const float4*)((SRC) + 4);     \
    WARR[0] = a_.x; WARR[1] = a_.y; WARR[2] = a_.z; WARR[3] = a_.w; \
    WARR[4] = b_.x; WARR[5] = b_.y; WARR[6] = b_.z; WARR[7] = b_.w; \
  } while (0)

#define CVT_STORE(BUFIDX, WARR)                                         \
  do {                                                                  \
    uint4 ph_, pl_;                                                     \
    unsigned short h0_, l0_, h1_, l1_;                                  \
    split2(WARR[0], h0_, l0_); split2(WARR[1], h1_, l1_);               \
    ph_.x = (unsigned)h0_ | ((unsigned)h1_ << 16);                      \
    pl_.x = (unsigned)l0_ | ((unsigned)l1_ << 16);                      \
    split2(WARR[2], h0_, l0_); split2(WARR[3], h1_, l1_);               \
    ph_.y = (unsigned)h0_ | ((unsigned)h1_ << 16);                      \
    pl_.y = (unsigned)l0_ | ((unsigned)l1_ << 16);                      \
    split2(WARR[4], h0_, l0_); split2(WARR[5], h1_, l1_);               \
    ph_.z = (unsigned)h0_ | ((unsigned)h1_ << 16);                      \
    pl_.z = (unsigned)l0_ | ((unsigned)l1_ << 16);                      \
    split2(WARR[6], h0_, l0_); split2(WARR[7], h1_, l1_);               \
    ph_.w = (unsigned)h0_ | ((unsigned)h1_ << 16);                      \
    pl_.w = (unsigned)l0_ | ((unsigned)l1_ << 16);                      \
    *(uint4*)(&Bh[BUFIDX][wdst]) = ph_;                                 \
    *(uint4*)(&Bl[BUFIDX][wdst]) = pl_;                                 \
  } while (0)

// 4-float variant (BN=16 tiles): float4 -> uint2 hi/lo, 8-byte LDS write
#define CVT_STORE4(BUFIDX, WREG)                                        \
  do {                                                                  \
    unsigned short h0_, l0_, h1_, l1_;                                  \
    uint2 ph_, pl_;                                                     \
    split2(WREG.x, h0_, l0_); split2(WREG.y, h1_, l1_);                 \
    ph_.x = (unsigned)h0_ | ((unsigned)h1_ << 16);                      \
    pl_.x = (unsigned)l0_ | ((unsigned)l1_ << 16);                      \
    split2(WREG.z, h0_, l0_); split2(WREG.w, h1_, l1_);                 \
    ph_.y = (unsigned)h0_ | ((unsigned)h1_ << 16);                      \
    pl_.y = (unsigned)l0_ | ((unsigned)l1_ << 16);                      \
    *(uint2*)(&Bh[BUFIDX][wdst]) = ph_;                                 \
    *(uint2*)(&Bl[BUFIDX][wdst]) = pl_;                                 \
  } while (0)

// K1: fused Q/K/V GEMM, split-precision (hh+hl+lh), depth-2 pipeline with
// COUNTED vmcnt barriers (prefetch stays in flight across s_barrier).
// BM=128, BN=32, BK=64, K=1024 (16 iters). grid = 3 mats x 64 n-tiles = 192.
__global__ __launch_bounds__(256, 2) void qkv_gemm(const ushort* __restrict__ xhi,
                                                   const ushort* __restrict__ xlo,
                                                   const float* __restrict__ Wq,
                                                   const float* __restrict__ Wk,
                                                   const float* __restrict__ Wv,
                                                   float* __restrict__ qkv,
                                                   float* __restrict__ stats) {
  __shared__ alignas(16) ushort Ah[2][128 * 64];
  __shared__ alignas(16) ushort Al[2][128 * 64];
  __shared__ alignas(16) ushort Bh[2][32 * 64];
  __shared__ alignas(16) ushort Bl[2][32 * 64];
  __shared__ float red[16];

  int mat = blockIdx.x >> 6;
  int nt  = blockIdx.x & 63;
  const float* W = (mat == 0) ? Wq : ((mat == 1) ? Wk : Wv);
  float* outp = qkv + mat * 262144;

  int tid = threadIdx.x, w = tid >> 6, lane = tid & 63;
  int l3 = lane >> 3, c7 = lane & 7;
  int swzc = (c7 ^ (l3 & 7)) << 3;             // pre-swizzled source chunk (elems)
  int wr2 = tid >> 3, wq2 = tid & 7;           // W staging: row, 8-float chunk
  const float* wsrc = W + (nt * 32 + wr2) * 1024 + wq2 * 8;
  int wdst = wr2 * 64 + ((wq2 ^ (wr2 & 7)) << 3);

  f32x4 acc[2][2];
#pragma unroll
  for (int m = 0; m < 2; ++m)
#pragma unroll
    for (int n = 0; n < 2; ++n) acc[m][n] = (f32x4){0.f, 0.f, 0.f, 0.f};

  float wreg0[8], wreg1[8];

  // prologue: stage t=0 -> buf0, t=1 -> buf1
#pragma unroll
  for (int j = 0; j < 4; ++j) {
    int row = (w * 4 + j) * 8 + l3;
    GLDS16(xhi + row * 1024 + 0 * 64 + swzc, &Ah[0][(w * 4 + j) * 512]);
    GLDS16(xlo + row * 1024 + 0 * 64 + swzc, &Al[0][(w * 4 + j) * 512]);
  }
  LOADW(wreg0, wsrc + 0 * 64);
#pragma unroll
  for (int j = 0; j < 4; ++j) {
    int row = (w * 4 + j) * 8 + l3;
    GLDS16(xhi + row * 1024 + 1 * 64 + swzc, &Ah[1][(w * 4 + j) * 512]);
    GLDS16(xlo + row * 1024 + 1 * 64 + swzc, &Al[1][(w * 4 + j) * 512]);
  }
  LOADW(wreg1, wsrc + 1 * 64);
  CVT_STORE(0, wreg0);
  __syncthreads();   // full drain once (safe prologue)

#pragma unroll
  for (int t = 0; t < 16; ++t) {
    const int c = t & 1;
    bf16x8 fah[2][2], fal[2][2], fbh[2][2], fbl[2][2];
#pragma unroll
    for (int ks = 0; ks < 2; ++ks) {
      int kc = ks * 4 + (lane >> 4);
#pragma unroll
      for (int m = 0; m < 2; ++m) {
        int r = w * 32 + m * 16 + (lane & 15);
        int sw = r * 64 + ((kc ^ (r & 7)) << 3);
        fah[ks][m] = *(const bf16x8*)(&Ah[c][sw]);
        fal[ks][m] = *(const bf16x8*)(&Al[c][sw]);
      }
#pragma unroll
      for (int n = 0; n < 2; ++n) {
        int r = n * 16 + (lane & 15);
        int sw = r * 64 + ((kc ^ (r & 7)) << 3);
        fbh[ks][n] = *(const bf16x8*)(&Bh[c][sw]);
        fbl[ks][n] = *(const bf16x8*)(&Bl[c][sw]);
      }
    }
    if (t < 14) {
      asm volatile("s_waitcnt lgkmcnt(0)" ::: "memory");  // own reads of buf c done
#pragma unroll
      for (int j = 0; j < 4; ++j) {
        int row = (w * 4 + j) * 8 + l3;
        GLDS16(xhi + row * 1024 + (t + 2) * 64 + swzc, &Ah[c][(w * 4 + j) * 512]);
        GLDS16(xlo + row * 1024 + (t + 2) * 64 + swzc, &Al[c][(w * 4 + j) * 512]);
      }
      if (c == 0) { LOADW(wreg0, wsrc + (t + 2) * 64); }
      else        { LOADW(wreg1, wsrc + (t + 2) * 64); }
    }
#pragma unroll
    for (int ks = 0; ks < 2; ++ks)
#pragma unroll
      for (int m = 0; m < 2; ++m)
#pragma unroll
        for (int n = 0; n < 2; ++n) {
          acc[m][n] = __builtin_amdgcn_mfma_f32_16x16x32_bf16(fah[ks][m], fbh[ks][n], acc[m][n], 0, 0, 0);
          acc[m][n] = __builtin_amdgcn_mfma_f32_16x16x32_bf16(fah[ks][m], fbl[ks][n], acc[m][n], 0, 0, 0);
          acc[m][n] = __builtin_amdgcn_mfma_f32_16x16x32_bf16(fal[ks][m], fbh[ks][n], acc[m][n], 0, 0, 0);
        }
    if (t < 15) {
      if (c == 0) { CVT_STORE(1, wreg1); }   // W(t+1) -> buf (t+1)&1
      else        { CVT_STORE(0, wreg0); }
      // counted barrier: keep this iter's 10 staged VMEM ops (8 glds + 2 loads)
      // in flight; everything older (incl. staging of t+1) must be done.
      if (t < 14) { asm volatile("s_waitcnt vmcnt(10) lgkmcnt(0)" ::: "memory"); }
      else        { asm volatile("s_waitcnt vmcnt(0) lgkmcnt(0)" ::: "memory"); }
      __builtin_amdgcn_sched_barrier(0);
      __builtin_amdgcn_s_barrier();
      __builtin_amdgcn_sched_barrier(0);
    }
  }

  // epilogue: store f32 + per-channel stats (channel = row&1 = r&1)
  float s0 = 0, q0 = 0, s1 = 0, q1 = 0;
#pragma unroll
  for (int m = 0; m < 2; ++m)
#pragma unroll
    for (int n = 0; n < 2; ++n)
#pragma unroll
      for (int r = 0; r < 4; ++r) {
        int row = w * 32 + m * 16 + (lane >> 4) * 4 + r;
        int col = nt * 32 + n * 16 + (lane & 15);
        float v = acc[m][n][r];
        outp[row * 2048 + col] = v;
        if (r & 1) { s1 += v; q1 += v * v; } else { s0 += v; q0 += v * v; }
      }
  s0 = wave_red(s0); q0 = wave_red(q0); s1 = wave_red(s1); q1 = wave_red(q1);
  if (lane == 0) { red[w * 4 + 0] = s0; red[w * 4 + 1] = q0; red[w * 4 + 2] = s1; red[w * 4 + 3] = q1; }
  __syncthreads();
  if (tid == 0) {
    float a0 = 0, a1 = 0, a2 = 0, a3 = 0;
    for (int i = 0; i < 4; ++i) { a0 += red[i * 4 + 0]; a1 += red[i * 4 + 1]; a2 += red[i * 4 + 2]; a3 += red[i * 4 + 3]; }
    atomicAdd(&stats[mat * 4 + 0], a0);
    atomicAdd(&stats[mat * 4 + 1], a1);
    atomicAdd(&stats[mat * 4 + 2], a2);
    atomicAdd(&stats[mat * 4 + 3], a3);
  }
}

// K2: per-(b,h) linear attention with on-the-fly BN affine; writes attn hi/lo bf16.
__global__ __launch_bounds__(256) void attn_kernel(const float* __restrict__ qkv,
                                                   const float* __restrict__ stats,
                                                   ushort* __restrict__ ahi,
                                                   ushort* __restrict__ alo,
                                                   const float* __restrict__ g_q, const float* __restrict__ b_q,
                                                   const float* __restrict__ g_k, const float* __restrict__ b_k,
                                                   const float* __restrict__ g_v, const float* __restrict__ b_v) {
  __shared__ float red[16];
  __shared__ float bc[4];
  int bh = blockIdx.x, b = bh >> 1, h = bh & 1;
  int tid = threadIdx.x, w = tid >> 6, lane = tid & 63;

  const float cnt = 131072.f;
  float qs[2], qo[2], kc_[2], ko[2], vs[2], vo[2];
#pragma unroll
  for (int c = 0; c < 2; ++c) {
    float m, var, inv;
    m = stats[0 + 2 * c] / cnt; var = stats[1 + 2 * c] / cnt - m * m; inv = rsqrtf(var + EPS);
    qs[c] = g_q[c] * inv; qo[c] = b_q[c] - m * qs[c];
    m = stats[4 + 2 * c] / cnt; var = stats[5 + 2 * c] / cnt - m * m; inv = rsqrtf(var + EPS);
    kc_[c] = g_k[c] * inv; ko[c] = b_k[c] - m * kc_[c];
    m = stats[8 + 2 * c] / cnt; var = stats[9 + 2 * c] / cnt - m * m; inv = rsqrtf(var + EPS);
    vs[c] = g_v[c] * inv; vo[c] = b_v[c] - m * vs[c];
  }

  const float* Q = qkv;
  const float* K = qkv + 262144;
  const float* V = qkv + 524288;
  const float* q0p = Q + (b * 2 + 0) * 2048 + h * 1024;
  const float* q1p = Q + (b * 2 + 1) * 2048 + h * 1024;
  const float* k0p = K + (b * 2 + 0) * 2048 + h * 1024;
  const float* k1p = K + (b * 2 + 1) * 2048 + h * 1024;
  const float* v0p = V + (b * 2 + 0) * 2048 + h * 1024;
  const float* v1p = V + (b * 2 + 1) * 2048 + h * 1024;

  float p00 = 0, p01 = 0, p10 = 0, p11 = 0;
#pragma unroll
  for (int i = 0; i < 4; ++i) {
    int d = tid + i * 256;
    float a0 = q0p[d] * qs[0] + qo[0];
    float a1 = q1p[d] * qs[1] + qo[1];
    float c0 = k0p[d] * kc_[0] + ko[0];
    float c1 = k1p[d] * kc_[1] + ko[1];
    p00 += a0 * c0; p01 += a0 * c1; p10 += a1 * c0; p11 += a1 * c1;
  }
  p00 = wave_red(p00); p01 = wave_red(p01); p10 = wave_red(p10); p11 = wave_red(p11);
  if (lane == 0) { red[w * 4 + 0] = p00; red[w * 4 + 1] = p01; red[w * 4 + 2] = p10; red[w * 4 + 3] = p11; }
  __syncthreads();
  if (tid < 4) bc[tid] = red[0 + tid] + red[4 + tid] + red[8 + tid] + red[12 + tid];
  __syncthreads();
  float s00 = bc[0], s01 = bc[1], s10 = bc[2], s11 = bc[3];
  float di0 = 1.f / (s00 + s01), di1 = 1.f / (s10 + s11);
  int o0 = (b * 2 + 0) * 2048 + h * 1024;
  int o1 = (b * 2 + 1) * 2048 + h * 1024;
#pragma unroll
  for (int i = 0; i < 4; ++i) {
    int d = tid + i * 256;
    float v0 = v0p[d] * vs[0] + vo[0];
    float v1 = v1p[d] * vs[1] + vo[1];
    float r0 = (s00 * v0 + s01 * v1) * di0;
    float r1 = (s10 * v0 + s11 * v1) * di1;
    unsigned short h_, l_;
    split2(r0, h_, l_); ahi[o0 + d] = h_; alo[o0 + d] = l_;
    split2(r1, h_, l_); ahi[o1 + d] = h_; alo[o1 + d] = l_;
  }
}

// K3: out GEMM full-K (128x2048 @ Wo^T -> 128x1024), split-precision.
// BM=64, BN=16, BK=64, K=2048 (32 iters). grid = 2 mt x 64 nt = 128.
// Writes proj WITH bias + deterministic per-block BN-stat partials (no atomics).
__global__ __launch_bounds__(256) void out_gemm(const ushort* __restrict__ ahi_g,
                                                const ushort* __restrict__ alo_g,
                                                const float* __restrict__ Wo,
                                                const float* __restrict__ bo,
                                                float* __restrict__ proj,
                                                float* __restrict__ so) {
  __shared__ alignas(16) ushort Ah[2][64 * 64];
  __shared__ alignas(16) ushort Al[2][64 * 64];
  __shared__ alignas(16) ushort Bh[2][16 * 64];
  __shared__ alignas(16) ushort Bl[2][16 * 64];
  __shared__ float red[16];

  int mt = blockIdx.x >> 6;
  int nt = blockIdx.x & 63;

  int tid = threadIdx.x, w = tid >> 6, lane = tid & 63;
  int l3 = lane >> 3, c7 = lane & 7;
  int swzc = (c7 ^ (l3 & 7)) << 3;
  int wr2 = tid >> 4, wq2 = tid & 15;    // W staging: 16 rows x 16 chunks of 4 f32
  const float* wsrc = Wo + (nt * 16 + wr2) * 2048 + wq2 * 4;
  int wdst = wr2 * 64 + (((wq2 >> 1) ^ (wr2 & 7)) << 3) + ((wq2 & 1) << 2);

  f32x4 acc = (f32x4){0.f, 0.f, 0.f, 0.f};
  float4 wregA, wregB;

  // prologue: stage t=0 -> buf0, t=1 -> buf1
#pragma unroll
  for (int j = 0; j < 2; ++j) {
    int gr = mt * 64 + (w * 2 + j) * 8 + l3;
    GLDS16(ahi_g + gr * 2048 + 0 * 64 + swzc, &Ah[0][(w * 2 + j) * 512]);
    GLDS16(alo_g + gr * 2048 + 0 * 64 + swzc, &Al[0][(w * 2 + j) * 512]);
  }
  wregA = *(const float4*)(wsrc + 0 * 64);
#pragma unroll
  for (int j = 0; j < 2; ++j) {
    int gr = mt * 64 + (w * 2 + j) * 8 + l3;
    GLDS16(ahi_g + gr * 2048 + 1 * 64 + swzc, &Ah[1][(w * 2 + j) * 512]);
    GLDS16(alo_g + gr * 2048 + 1 * 64 + swzc, &Al[1][(w * 2 + j) * 512]);
  }
  wregB = *(const float4*)(wsrc + 1 * 64);
  CVT_STORE4(0, wregA);
  __syncthreads();   // full drain once

#pragma unroll
  for (int t = 0; t < 32; ++t) {
    const int c = t & 1;
    bf16x8 fah[2], fal[2], fbh[2], fbl[2];
#pragma unroll
    for (int ks = 0; ks < 2; ++ks) {
      int kc = ks * 4 + (lane >> 4);
      int ra = w * 16 + (lane & 15);
      int sa = ra * 64 + ((kc ^ (ra & 7)) << 3);
      fah[ks] = *(const bf16x8*)(&Ah[c][sa]);
      fal[ks] = *(const bf16x8*)(&Al[c][sa]);
      int rb = lane & 15;
      int sb = rb * 64 + ((kc ^ (rb & 7)) << 3);
      fbh[ks] = *(const bf16x8*)(&Bh[c][sb]);
      fbl[ks] = *(const bf16x8*)(&Bl[c][sb]);
    }
    if (t < 30) {
      asm volatile("s_waitcnt lgkmcnt(0)" ::: "memory");
#pragma unroll
      for (int j = 0; j < 2; ++j) {
        int gr = mt * 64 + (w * 2 + j) * 8 + l3;
        GLDS16(ahi_g + gr * 2048 + (t + 2) * 64 + swzc, &Ah[c][(w * 2 + j) * 512]);
        GLDS16(alo_g + gr * 2048 + (t + 2) * 64 + swzc, &Al[c][(w * 2 + j) * 512]);
      }
      if (c == 0) { wregA = *(const float4*)(wsrc + (t + 2) * 64); }
      else        { wregB = *(const float4*)(wsrc + (t + 2) * 64); }
    }
#pragma unroll
    for (int ks = 0; ks < 2; ++ks) {
      acc = __builtin_amdgcn_mfma_f32_16x16x32_bf16(fah[ks], fbh[ks], acc, 0, 0, 0);
      acc = __builtin_amdgcn_mfma_f32_16x16x32_bf16(fah[ks], fbl[ks], acc, 0, 0, 0);
      acc = __builtin_amdgcn_mfma_f32_16x16x32_bf16(fal[ks], fbh[ks], acc, 0, 0, 0);
    }
    if (t < 31) {
      if (c == 0) { CVT_STORE4(1, wregB); }
      else        { CVT_STORE4(0, wregA); }
      // counted barrier: 5 staged VMEM ops this iter (4 glds + 1 load)
      if (t < 30) { asm volatile("s_waitcnt vmcnt(5) lgkmcnt(0)" ::: "memory"); }
      else        { asm volatile("s_waitcnt vmcnt(0) lgkmcnt(0)" ::: "memory"); }
      __builtin_amdgcn_sched_barrier(0);
      __builtin_amdgcn_s_barrier();
      __builtin_amdgcn_sched_barrier(0);
    }
  }

  // epilogue: proj = acc + bias; per-channel (row parity = r&1) partial stats
  int col = nt * 16 + (lane & 15);
  float bov = bo[col];
  float s0 = 0, q0 = 0, s1 = 0, q1 = 0;
#pragma unroll
  for (int r = 0; r < 4; ++r) {
    int grow = mt * 64 + w * 16 + (lane >> 4) * 4 + r;
    float v = acc[r] + bov;
    proj[grow * 1024 + col] = v;
    if (r & 1) { s1 += v; q1 += v * v; } else { s0 += v; q0 += v * v; }
  }
  s0 = wave_red(s0); q0 = wave_red(q0); s1 = wave_red(s1); q1 = wave_red(q1);
  if (lane == 0) { red[w * 4 + 0] = s0; red[w * 4 + 1] = q0; red[w * 4 + 2] = s1; red[w * 4 + 3] = q1; }
  __syncthreads();
  if (tid == 0) {
    float a0 = 0, a1 = 0, a2 = 0, a3 = 0;
    for (int i = 0; i < 4; ++i) { a0 += red[i * 4 + 0]; a1 += red[i * 4 + 1]; a2 += red[i * 4 + 2]; a3 += red[i * 4 + 3]; }
    *(float4*)(so + blockIdx.x * 4) = (float4){a0, a1, a2, a3};
  }
}

// K4: deterministic reduce of 128 stat partials + final BN normalize.
__global__ __launch_bounds__(256) void final_kernel(const float* __restrict__ proj,
                                                    const float* __restrict__ so,
                                                    const float* __restrict__ g_bn,
                                                    const float* __restrict__ b_bn,
                                                    float* __restrict__ out) {
  __shared__ float sm[8];
  int tid = threadIdx.x, w = tid >> 6;
  int r = blockIdx.x;
  if (tid < 128) {
    float4 p = *(const float4*)(so + tid * 4);
    float a0 = wave_red(p.x), a1 = wave_red(p.y), a2 = wave_red(p.z), a3 = wave_red(p.w);
    if ((tid & 63) == 0) { sm[w * 4 + 0] = a0; sm[w * 4 + 1] = a1; sm[w * 4 + 2] = a2; sm[w * 4 + 3] = a3; }
  }
  __syncthreads();
  float s0 = sm[0] + sm[4], q0 = sm[1] + sm[5];
  float s1 = sm[2] + sm[6], q1 = sm[3] + sm[7];
  int ch = r & 1;
  float m = (ch ? s1 : s0) / 65536.f;
  float var = (ch ? q1 : q0) / 65536.f - m * m;
  float sc = g_bn[ch] * rsqrtf(var + EPS);
  float sh = b_bn[ch] - m * sc;
  float4 v = *(const float4*)(proj + r * 1024 + tid * 4);
  float4 o = {v.x * sc + sh, v.y * sc + sh, v.z * sc + sh, v.w * sc + sh};
  *(float4*)(out + r * 1024 + tid * 4) = o;
}

extern "C" void kernel_launch(void* const* d_in, const int* in_sizes, int n_in,
                              void* d_out, int out_size, void* d_ws, size_t ws_size,
                              hipStream_t stream) {
  (void)in_sizes; (void)n_in; (void)out_size; (void)ws_size;
  const float* x    = (const float*)d_in[0];
  const float* Wq   = (const float*)d_in[1];
  const float* Wk   = (const float*)d_in[2];
  const float* Wv   = (const float*)d_in[3];
  const float* Wo   = (const float*)d_in[4];
  const float* bo   = (const float*)d_in[5];
  const float* g_q  = (const float*)d_in[6];
  const float* b_q  = (const float*)d_in[7];
  const float* g_k  = (const float*)d_in[8];
  const float* b_k  = (const float*)d_in[9];
  const float* g_v  = (const float*)d_in[10];
  const float* b_v  = (const float*)d_in[11];
  const float* g_bn = (const float*)d_in[12];
  const float* b_bn = (const float*)d_in[13];
  char* ws = (char*)d_ws;
  float* out = (float*)d_out;

  float*  stats = (float*)(ws + OFF_STATS);
  ushort* xhi   = (ushort*)(ws + OFF_XHI);
  ushort* xlo   = (ushort*)(ws + OFF_XLO);
  float*  qkv   = (float*)(ws + OFF_Q);
  ushort* ahi   = (ushort*)(ws + OFF_AHI);
  ushort* alo   = (ushort*)(ws + OFF_ALO);
  float*  so    = (float*)(ws + OFF_SO);
  float*  proj  = (float*)(ws + OFF_PROJ);

  hipLaunchKernelGGL(prep_kernel,  dim3(128), dim3(256), 0, stream, x, xhi, xlo, stats);
  hipLaunchKernelGGL(qkv_gemm,     dim3(192), dim3(256), 0, stream, xhi, xlo, Wq, Wk, Wv, qkv, stats);
  hipLaunchKernelGGL(attn_kernel,  dim3(128), dim3(256), 0, stream, qkv, stats, ahi, alo,
                     g_q, b_q, g_k, b_k, g_v, b_v);
  hipLaunchKernelGGL(out_gemm,     dim3(128), dim3(256), 0, stream, ahi, alo, Wo, bo, proj, so);
  hipLaunchKernelGGL(final_kernel, dim3(128), dim3(256), 0, stream, proj, so, g_bn, b_bn, out);
}

// Round 6
// 45.734 us; speedup vs baseline: 3.4838x; 1.2352x over previous
//
#include <hip/hip_runtime.h>
#include <stdint.h>

typedef __bf16 bf16x8 __attribute__((ext_vector_type(8)));
typedef float f32x4 __attribute__((ext_vector_type(4)));

#define EPS 1e-5f

// ---- workspace layout (bytes) ----
#define OFF_SQ    0                       // 192*4 f32: per-block qkv BN partials
#define OFF_Q     4096                    // q,k,v f32 128x2048 each = 3 MB
#define OFF_AHI   (OFF_Q + 3145728)       // attn bf16 128x2048 = 512 KB
#define OFF_SO    (OFF_AHI + 524288)      // 128*4 f32: out BN partials
#define OFF_PROJ  (OFF_SO + 4096)         // 128x1024 f32 = 512 KB

static __device__ __forceinline__ unsigned short f2b(float f) {
  return __builtin_bit_cast(unsigned short, (__bf16)f);
}

__device__ __forceinline__ float wave_red(float v) {
#pragma unroll
  for (int o = 32; o > 0; o >>= 1) v += __shfl_down(v, o);
  return v;
}

#define GLDS16(g, l)                                             \
  __builtin_amdgcn_global_load_lds(                              \
      (const __attribute__((address_space(1))) void*)(g),        \
      (__attribute__((address_space(3))) void*)(l), 16, 0, 0)

// read 8 consecutive-K f32 from LDS (pre-swizzled pair of 16B chunks) and
// split into hi/lo bf16x8
static __device__ __forceinline__ void frag_split(const float* base, int p0,
                                                  bf16x8& hi, bf16x8& lo) {
  float4 v0 = *(const float4*)(base + p0 * 4);
  float4 v1 = *(const float4*)(base + p0 * 4 + 4);
  float a[8] = {v0.x, v0.y, v0.z, v0.w, v1.x, v1.y, v1.z, v1.w};
#pragma unroll
  for (int i = 0; i < 8; ++i) {
    __bf16 h = (__bf16)a[i];
    hi[i] = h;
    lo[i] = (__bf16)(a[i] - (float)h);
  }
}
static __device__ __forceinline__ bf16x8 frag_cvt(const float* base, int p0) {
  float4 v0 = *(const float4*)(base + p0 * 4);
  float4 v1 = *(const float4*)(base + p0 * 4 + 4);
  bf16x8 r;
  r[0] = (__bf16)v0.x; r[1] = (__bf16)v0.y; r[2] = (__bf16)v0.z; r[3] = (__bf16)v0.w;
  r[4] = (__bf16)v1.x; r[5] = (__bf16)v1.y; r[6] = (__bf16)v1.z; r[7] = (__bf16)v1.w;
  return r;
}

// K1: fused Q/K/V GEMM, split-precision (hh+hl+lh). A = x f32 staged via glds,
// B = W f32 staged via glds; hi/lo conversion at fragment read. 3-buffer
// rotation, stage 2 tiles ahead into the buffer freed at the last barrier.
// BM=128, BN=32, BK=64, K=1024 (16 iters). grid = 3 mats x 64 nt = 192.
__global__ __launch_bounds__(256) void qkv_gemm(const float* __restrict__ x,
                                                const float* __restrict__ Wq,
                                                const float* __restrict__ Wk,
                                                const float* __restrict__ Wv,
                                                float* __restrict__ qkv,
                                                float* __restrict__ sq) {
  __shared__ alignas(16) float Af[3][128 * 64];   // 96 KB
  __shared__ alignas(16) float Bf[3][32 * 64];    // 24 KB
  __shared__ float red[16];

  int mat = blockIdx.x >> 6;
  int nt  = blockIdx.x & 63;
  const float* W = (mat == 0) ? Wq : ((mat == 1) ? Wk : Wv);
  float* outp = qkv + mat * 262144;

  int tid = threadIdx.x, w = tid >> 6, lane = tid & 63;
  int rsel = lane >> 4, ch = lane & 15;

#define STAGE_Q(c, tt) do {                                                      \
    _Pragma("unroll")                                                            \
    for (int j = 0; j < 8; ++j) {                                                \
      int rl = w * 32 + j * 4 + rsel;                                            \
      GLDS16(x + rl * 1024 + (tt) * 64 + ((ch ^ ((rl & 7) << 1)) << 2),          \
             &Af[c][(w * 32 + j * 4) * 64]);                                     \
    }                                                                            \
    _Pragma("unroll")                                                            \
    for (int j = 0; j < 2; ++j) {                                                \
      int rl = w * 8 + j * 4 + rsel;                                             \
      GLDS16(W + (nt * 32 + rl) * 1024 + (tt) * 64 +                             \
                 ((ch ^ ((rl & 7) << 1)) << 2),                                  \
             &Bf[c][(w * 8 + j * 4) * 64]);                                      \
    }                                                                            \
  } while (0)

  f32x4 acc[2][2];
#pragma unroll
  for (int m = 0; m < 2; ++m)
#pragma unroll
    for (int n = 0; n < 2; ++n) acc[m][n] = (f32x4){0.f, 0.f, 0.f, 0.f};

  // prologue: tiles 0,1 -> bufs 0,1
  STAGE_Q(0, 0);
  STAGE_Q(1, 1);
  __syncthreads();

#pragma unroll
  for (int t = 0; t < 16; ++t) {
    const int c = t % 3;
    bf16x8 fah[2][2], fal[2][2], fbh[2][2], fbl[2][2];
#pragma unroll
    for (int ks = 0; ks < 2; ++ks) {
      int kc = ks * 4 + rsel;
#pragma unroll
      for (int m = 0; m < 2; ++m) {
        int ra = w * 32 + m * 16 + (lane & 15);
        int p0 = (kc * 2) ^ ((ra & 7) << 1);
        frag_split(&Af[c][ra * 64], p0, fah[ks][m], fal[ks][m]);
      }
#pragma unroll
      for (int n = 0; n < 2; ++n) {
        int rb = n * 16 + (lane & 15);
        int p0 = (kc * 2) ^ ((rb & 7) << 1);
        frag_split(&Bf[c][rb * 64], p0, fbh[ks][n], fbl[ks][n]);
      }
    }
    if (t < 14) { STAGE_Q((t + 2) % 3, t + 2); }   // into freed buffer
#pragma unroll
    for (int ks = 0; ks < 2; ++ks)
#pragma unroll
      for (int m = 0; m < 2; ++m)
#pragma unroll
        for (int n = 0; n < 2; ++n) {
          acc[m][n] = __builtin_amdgcn_mfma_f32_16x16x32_bf16(fah[ks][m], fbh[ks][n], acc[m][n], 0, 0, 0);
          acc[m][n] = __builtin_amdgcn_mfma_f32_16x16x32_bf16(fah[ks][m], fbl[ks][n], acc[m][n], 0, 0, 0);
          acc[m][n] = __builtin_amdgcn_mfma_f32_16x16x32_bf16(fal[ks][m], fbh[ks][n], acc[m][n], 0, 0, 0);
        }
    if (t < 15) {
      if (t < 14) { asm volatile("s_waitcnt vmcnt(10) lgkmcnt(0)" ::: "memory"); }
      else        { asm volatile("s_waitcnt vmcnt(0) lgkmcnt(0)" ::: "memory"); }
      __builtin_amdgcn_sched_barrier(0);
      __builtin_amdgcn_s_barrier();
      __builtin_amdgcn_sched_barrier(0);
    }
  }
#undef STAGE_Q

  // epilogue: store f32 + per-channel (row parity) partial stats, deterministic
  float s0 = 0, q0 = 0, s1 = 0, q1 = 0;
#pragma unroll
  for (int m = 0; m < 2; ++m)
#pragma unroll
    for (int n = 0; n < 2; ++n)
#pragma unroll
      for (int r = 0; r < 4; ++r) {
        int row = w * 32 + m * 16 + (lane >> 4) * 4 + r;
        int col = nt * 32 + n * 16 + (lane & 15);
        float v = acc[m][n][r];
        outp[row * 2048 + col] = v;
        if (r & 1) { s1 += v; q1 += v * v; } else { s0 += v; q0 += v * v; }
      }
  s0 = wave_red(s0); q0 = wave_red(q0); s1 = wave_red(s1); q1 = wave_red(q1);
  if (lane == 0) { red[w * 4 + 0] = s0; red[w * 4 + 1] = q0; red[w * 4 + 2] = s1; red[w * 4 + 3] = q1; }
  __syncthreads();
  if (tid == 0) {
    float a0 = 0, a1 = 0, a2 = 0, a3 = 0;
    for (int i = 0; i < 4; ++i) { a0 += red[i * 4 + 0]; a1 += red[i * 4 + 1]; a2 += red[i * 4 + 2]; a3 += red[i * 4 + 3]; }
    *(float4*)(sq + blockIdx.x * 4) = (float4){a0, a1, a2, a3};
  }
}

// K2: per-(b,h) linear attention; reduces qkv stat partials in-kernel;
// writes attn as single bf16.
__global__ __launch_bounds__(256) void attn_kernel(const float* __restrict__ qkv,
                                                   const float* __restrict__ sq,
                                                   ushort* __restrict__ ahi,
                                                   const float* __restrict__ g_q, const float* __restrict__ b_q,
                                                   const float* __restrict__ g_k, const float* __restrict__ b_k,
                                                   const float* __restrict__ g_v, const float* __restrict__ b_v) {
  __shared__ float sm[12];
  __shared__ float red[16];
  __shared__ float bc[4];
  int bh = blockIdx.x, b = bh >> 1, h = bh & 1;
  int tid = threadIdx.x, w = tid >> 6, lane = tid & 63;

  // reduce 192 per-block partials: wave w (w<3) handles mat w (64 entries)
  if (tid < 192) {
    float4 p = *(const float4*)(sq + tid * 4);
    float a0 = wave_red(p.x), a1 = wave_red(p.y), a2 = wave_red(p.z), a3 = wave_red(p.w);
    if (lane == 0) { sm[w * 4 + 0] = a0; sm[w * 4 + 1] = a1; sm[w * 4 + 2] = a2; sm[w * 4 + 3] = a3; }
  }
  __syncthreads();

  const float cnt = 131072.f;
  float qs[2], qo[2], kc_[2], ko[2], vs[2], vo[2];
#pragma unroll
  for (int c = 0; c < 2; ++c) {
    float m, var, inv;
    m = sm[0 + 2 * c] / cnt; var = sm[1 + 2 * c] / cnt - m * m; inv = rsqrtf(var + EPS);
    qs[c] = g_q[c] * inv; qo[c] = b_q[c] - m * qs[c];
    m = sm[4 + 2 * c] / cnt; var = sm[5 + 2 * c] / cnt - m * m; inv = rsqrtf(var + EPS);
    kc_[c] = g_k[c] * inv; ko[c] = b_k[c] - m * kc_[c];
    m = sm[8 + 2 * c] / cnt; var = sm[9 + 2 * c] / cnt - m * m; inv = rsqrtf(var + EPS);
    vs[c] = g_v[c] * inv; vo[c] = b_v[c] - m * vs[c];
  }

  const float* Q = qkv;
  const float* K = qkv + 262144;
  const float* V = qkv + 524288;
  const float* q0p = Q + (b * 2 + 0) * 2048 + h * 1024;
  const float* q1p = Q + (b * 2 + 1) * 2048 + h * 1024;
  const float* k0p = K + (b * 2 + 0) * 2048 + h * 1024;
  const float* k1p = K + (b * 2 + 1) * 2048 + h * 1024;
  const float* v0p = V + (b * 2 + 0) * 2048 + h * 1024;
  const float* v1p = V + (b * 2 + 1) * 2048 + h * 1024;

  float p00 = 0, p01 = 0, p10 = 0, p11 = 0;
#pragma unroll
  for (int i = 0; i < 4; ++i) {
    int d = tid + i * 256;
    float a0 = q0p[d] * qs[0] + qo[0];
    float a1 = q1p[d] * qs[1] + qo[1];
    float c0 = k0p[d] * kc_[0] + ko[0];
    float c1 = k1p[d] * kc_[1] + ko[1];
    p00 += a0 * c0; p01 += a0 * c1; p10 += a1 * c0; p11 += a1 * c1;
  }
  p00 = wave_red(p00); p01 = wave_red(p01); p10 = wave_red(p10); p11 = wave_red(p11);
  if (lane == 0) { red[w * 4 + 0] = p00; red[w * 4 + 1] = p01; red[w * 4 + 2] = p10; red[w * 4 + 3] = p11; }
  __syncthreads();
  if (tid < 4) bc[tid] = red[0 + tid] + red[4 + tid] + red[8 + tid] + red[12 + tid];
  __syncthreads();
  float s00 = bc[0], s01 = bc[1], s10 = bc[2], s11 = bc[3];
  float di0 = 1.f / (s00 + s01), di1 = 1.f / (s10 + s11);
  int o0 = (b * 2 + 0) * 2048 + h * 1024;
  int o1 = (b * 2 + 1) * 2048 + h * 1024;
#pragma unroll
  for (int i = 0; i < 4; ++i) {
    int d = tid + i * 256;
    float v0 = v0p[d] * vs[0] + vo[0];
    float v1 = v1p[d] * vs[1] + vo[1];
    ahi[o0 + d] = f2b((s00 * v0 + s01 * v1) * di0);
    ahi[o1 + d] = f2b((s10 * v0 + s11 * v1) * di1);
  }
}

// K3: out GEMM full-K (128x2048 @ Wo^T -> 128x1024), plain bf16.
// A = attn bf16 via glds; B = Wo f32 via glds, cvt on read.
// BM=64, BN=16, BK=128, K=2048 (16 iters). grid = 2 mt x 64 nt = 128.
__global__ __launch_bounds__(256) void out_gemm(const ushort* __restrict__ ahi,
                                                const float* __restrict__ Wo,
                                                const float* __restrict__ bo,
                                                float* __restrict__ proj,
                                                float* __restrict__ so) {
  __shared__ alignas(16) ushort Ab[3][64 * 128];   // 48 KB
  __shared__ alignas(16) float  Bf[3][16 * 128];   // 24 KB
  __shared__ float red[16];

  int mt = blockIdx.x >> 6;
  int nt = blockIdx.x & 63;

  int tid = threadIdx.x, w = tid >> 6, lane = tid & 63;
  int rsel4 = lane >> 4, ch16 = lane & 15;
  int rsel2 = lane >> 5, ch32 = lane & 31;

#define STAGE_O(c, tt) do {                                                      \
    _Pragma("unroll")                                                            \
    for (int j = 0; j < 4; ++j) {                                                \
      int rl = w * 16 + j * 4 + rsel4;                                           \
      GLDS16(ahi + (mt * 64 + rl) * 2048 + (tt) * 128 +                          \
                 ((ch16 ^ (rl & 7)) << 3),                                       \
             &Ab[c][(w * 16 + j * 4) * 128]);                                    \
    }                                                                            \
    _Pragma("unroll")                                                            \
    for (int j = 0; j < 2; ++j) {                                                \
      int rl = w * 4 + j * 2 + rsel2;                                            \
      GLDS16(Wo + (nt * 16 + rl) * 2048 + (tt) * 128 +                           \
                 ((ch32 ^ ((rl & 7) << 1)) << 2),                                \
             &Bf[c][(w * 4 + j * 2) * 128]);                                     \
    }                                                                            \
  } while (0)

  f32x4 acc = (f32x4){0.f, 0.f, 0.f, 0.f};

  STAGE_O(0, 0);
  STAGE_O(1, 1);
  __syncthreads();

#pragma unroll
  for (int t = 0; t < 16; ++t) {
    const int c = t % 3;
    bf16x8 fa[4], fb[4];
#pragma unroll
    for (int ks = 0; ks < 4; ++ks) {
      int kc = ks * 4 + rsel4;
      int ra = w * 16 + (lane & 15);
      fa[ks] = *(const bf16x8*)(&Ab[c][ra * 128 + ((kc ^ (ra & 7)) << 3)]);
      int rb = lane & 15;
      int p0 = (kc * 2) ^ ((rb & 7) << 1);
      fb[ks] = frag_cvt(&Bf[c][rb * 128], p0);
    }
    if (t < 14) { STAGE_O((t + 2) % 3, t + 2); }
#pragma unroll
    for (int ks = 0; ks < 4; ++ks)
      acc = __builtin_amdgcn_mfma_f32_16x16x32_bf16(fa[ks], fb[ks], acc, 0, 0, 0);
    if (t < 15) {
      if (t < 14) { asm volatile("s_waitcnt vmcnt(6) lgkmcnt(0)" ::: "memory"); }
      else        { asm volatile("s_waitcnt vmcnt(0) lgkmcnt(0)" ::: "memory"); }
      __builtin_amdgcn_sched_barrier(0);
      __builtin_amdgcn_s_barrier();
      __builtin_amdgcn_sched_barrier(0);
    }
  }
#undef STAGE_O

  // epilogue: proj = acc + bias; per-channel partial stats (deterministic)
  int col = nt * 16 + (lane & 15);
  float bov = bo[col];
  float s0 = 0, q0 = 0, s1 = 0, q1 = 0;
#pragma unroll
  for (int r = 0; r < 4; ++r) {
    int grow = mt * 64 + w * 16 + (lane >> 4) * 4 + r;
    float v = acc[r] + bov;
    proj[grow * 1024 + col] = v;
    if (r & 1) { s1 += v; q1 += v * v; } else { s0 += v; q0 += v * v; }
  }
  s0 = wave_red(s0); q0 = wave_red(q0); s1 = wave_red(s1); q1 = wave_red(q1);
  if (lane == 0) { red[w * 4 + 0] = s0; red[w * 4 + 1] = q0; red[w * 4 + 2] = s1; red[w * 4 + 3] = q1; }
  __syncthreads();
  if (tid == 0) {
    float a0 = 0, a1 = 0, a2 = 0, a3 = 0;
    for (int i = 0; i < 4; ++i) { a0 += red[i * 4 + 0]; a1 += red[i * 4 + 1]; a2 += red[i * 4 + 2]; a3 += red[i * 4 + 3]; }
    *(float4*)(so + blockIdx.x * 4) = (float4){a0, a1, a2, a3};
  }
}

// K4: reduce 128 stat partials + final BN normalize.
__global__ __launch_bounds__(256) void final_kernel(const float* __restrict__ proj,
                                                    const float* __restrict__ so,
                                                    const float* __restrict__ g_bn,
                                                    const float* __restrict__ b_bn,
                                                    float* __restrict__ out) {
  __shared__ float sm[8];
  int tid = threadIdx.x, w = tid >> 6;
  int r = blockIdx.x;
  if (tid < 128) {
    float4 p = *(const float4*)(so + tid * 4);
    float a0 = wave_red(p.x), a1 = wave_red(p.y), a2 = wave_red(p.z), a3 = wave_red(p.w);
    if ((tid & 63) == 0) { sm[w * 4 + 0] = a0; sm[w * 4 + 1] = a1; sm[w * 4 + 2] = a2; sm[w * 4 + 3] = a3; }
  }
  __syncthreads();
  float s0 = sm[0] + sm[4], q0 = sm[1] + sm[5];
  float s1 = sm[2] + sm[6], q1 = sm[3] + sm[7];
  int ch = r & 1;
  float m = (ch ? s1 : s0) / 65536.f;
  float var = (ch ? q1 : q0) / 65536.f - m * m;
  float sc = g_bn[ch] * rsqrtf(var + EPS);
  float sh = b_bn[ch] - m * sc;
  float4 v = *(const float4*)(proj + r * 1024 + tid * 4);
  float4 o = {v.x * sc + sh, v.y * sc + sh, v.z * sc + sh, v.w * sc + sh};
  *(float4*)(out + r * 1024 + tid * 4) = o;
}

extern "C" void kernel_launch(void* const* d_in, const int* in_sizes, int n_in,
                              void* d_out, int out_size, void* d_ws, size_t ws_size,
                              hipStream_t stream) {
  (void)in_sizes; (void)n_in; (void)out_size; (void)ws_size;
  const float* x    = (const float*)d_in[0];
  const float* Wq   = (const float*)d_in[1];
  const float* Wk   = (const float*)d_in[2];
  const float* Wv   = (const float*)d_in[3];
  const float* Wo   = (const float*)d_in[4];
  const float* bo   = (const float*)d_in[5];
  const float* g_q  = (const float*)d_in[6];
  const float* b_q  = (const float*)d_in[7];
  const float* g_k  = (const float*)d_in[8];
  const float* b_k  = (const float*)d_in[9];
  const float* g_v  = (const float*)d_in[10];
  const float* b_v  = (const float*)d_in[11];
  const float* g_bn = (const float*)d_in[12];
  const float* b_bn = (const float*)d_in[13];
  char* ws = (char*)d_ws;
  float* out = (float*)d_out;

  float*  sq   = (float*)(ws + OFF_SQ);
  float*  qkv  = (float*)(ws + OFF_Q);
  ushort* ahi  = (ushort*)(ws + OFF_AHI);
  float*  so   = (float*)(ws + OFF_SO);
  float*  proj = (float*)(ws + OFF_PROJ);

  hipLaunchKernelGGL(qkv_gemm,     dim3(192), dim3(256), 0, stream, x, Wq, Wk, Wv, qkv, sq);
  hipLaunchKernelGGL(attn_kernel,  dim3(128), dim3(256), 0, stream, qkv, sq, ahi,
                     g_q, b_q, g_k, b_k, g_v, b_v);
  hipLaunchKernelGGL(out_gemm,     dim3(128), dim3(256), 0, stream, ahi, Wo, bo, proj, so);
  hipLaunchKernelGGL(final_kernel, dim3(128), dim3(256), 0, stream, proj, so, g_bn, b_bn, out);
}